// Round 1
// baseline (9989.252 us; speedup 1.0000x reference)
//
#include <hip/hip_runtime.h>
#include <math.h>

// ---------------------------------------------------------------------------
// VQ-VAE forward, fp32 baseline.
// Shapes: x[16,3,128,128] -> enc -> z[16,64,32,32] -> VQ(512 codes, D=64)
//         -> dec -> recons[16,3,128,128], plus embedding/commitment losses
// (identical in forward value).
// ---------------------------------------------------------------------------

#define NB 16      // batch
#define H1C 256    // hidden dim
#define H0C 128
#define DEMB 64
#define KCODE 512

template<int ACT>
__device__ __forceinline__ float actf(float v) {
    if (ACT == 1) return fmaxf(v, 0.f);              // relu
    if (ACT == 2) return v > 0.f ? v : 0.01f * v;    // leaky relu
    if (ACT == 3) return tanhf(v);
    return v;
}

// ------------------------- conv0: 4x4 s2 p1, Cin=3 -------------------------
// in [16,3,128,128] -> out [16,128,64,64], bias + lrelu
__global__ __launch_bounds__(256) void conv0_k(const float* __restrict__ x,
        const float* __restrict__ W, const float* __restrict__ bias,
        float* __restrict__ out) {
    int n = blockIdx.z, oc = blockIdx.y;
    int pix = blockIdx.x * 256 + threadIdx.x;     // 0..4095
    int oy = pix >> 6, ox = pix & 63;
    const float* xn = x + (size_t)n * 3 * 16384;
    float acc = 0.f;
#pragma unroll
    for (int ic = 0; ic < 3; ic++) {
        const float* wp = W + ((size_t)oc * 3 + ic) * 16;
        const float* xp = xn + (size_t)ic * 16384;
#pragma unroll
        for (int ky = 0; ky < 4; ky++) {
            int iy = oy * 2 - 1 + ky;
            if ((unsigned)iy >= 128u) continue;
#pragma unroll
            for (int kx = 0; kx < 4; kx++) {
                int ix = ox * 2 - 1 + kx;
                if ((unsigned)ix >= 128u) continue;
                acc += wp[ky * 4 + kx] * xp[iy * 128 + ix];
            }
        }
    }
    acc += bias[oc];
    out[((size_t)n * 128 + oc) * 4096 + pix] = actf<2>(acc);
}

// ------------------- conv1: 4x4 s2 p1, Cin=128 -> Cout=256 -----------------
// in [16,128,64,64] -> out [16,256,32,32], bias + lrelu
__global__ __launch_bounds__(256) void conv1_k(const float* __restrict__ in,
        const float* __restrict__ W, const float* __restrict__ bias,
        float* __restrict__ out) {
    int oc0 = blockIdx.x * 8, n = blockIdx.y;
    int tid = threadIdx.x;
    __shared__ float sIn[66 * 66];
    __shared__ float sW[16 * 8];
    float acc[4][8];
#pragma unroll
    for (int i = 0; i < 4; i++)
#pragma unroll
        for (int o = 0; o < 8; o++) acc[i][o] = 0.f;
    const float* inN = in + (size_t)n * 128 * 4096;
    for (int ic = 0; ic < 128; ic++) {
        for (int t = tid; t < 66 * 66; t += 256) {
            int iy = t / 66 - 1, ix = t % 66 - 1;
            float v = 0.f;
            if ((unsigned)iy < 64u && (unsigned)ix < 64u)
                v = inN[(size_t)ic * 4096 + iy * 64 + ix];
            sIn[t] = v;
        }
        if (tid < 128) {
            int k = tid >> 3, o = tid & 7;
            sW[tid] = W[((size_t)(oc0 + o) * 128 + ic) * 16 + k];
        }
        __syncthreads();
#pragma unroll
        for (int k = 0; k < 16; k++) {
            int ky = k >> 2, kx = k & 3;
            float4 w0 = *(const float4*)(sW + k * 8);
            float4 w1 = *(const float4*)(sW + k * 8 + 4);
#pragma unroll
            for (int i = 0; i < 4; i++) {
                int p = tid + 256 * i; int r = p >> 5, c = p & 31;
                float xv = sIn[(2 * r + ky) * 66 + 2 * c + kx];
                acc[i][0] += w0.x * xv; acc[i][1] += w0.y * xv;
                acc[i][2] += w0.z * xv; acc[i][3] += w0.w * xv;
                acc[i][4] += w1.x * xv; acc[i][5] += w1.y * xv;
                acc[i][6] += w1.z * xv; acc[i][7] += w1.w * xv;
            }
        }
        __syncthreads();
    }
#pragma unroll
    for (int o = 0; o < 8; o++) {
        float b = bias[oc0 + o];
#pragma unroll
        for (int i = 0; i < 4; i++) {
            float v = acc[i][o] + b;
            out[((size_t)n * 256 + oc0 + o) * 1024 + tid + 256 * i] = actf<2>(v);
        }
    }
}

// ------------------- conv3x3 s1 p1 on 32x32, Cout=256 ----------------------
template<int CIN, int ACT, bool HASB>
__global__ __launch_bounds__(256) void conv3x3_k(const float* __restrict__ in,
        const float* __restrict__ W, const float* __restrict__ bias,
        float* __restrict__ out) {
    int oc0 = blockIdx.x * 8, n = blockIdx.y;
    int tid = threadIdx.x;
    __shared__ float sIn[4 * 1156];   // 4 ic planes, 34x34
    __shared__ float sW[4 * 72];      // [ic][9 taps][8 oc]
    float acc[4][8];
#pragma unroll
    for (int i = 0; i < 4; i++)
#pragma unroll
        for (int o = 0; o < 8; o++) acc[i][o] = 0.f;
    int r[4], c[4];
#pragma unroll
    for (int i = 0; i < 4; i++) { int p = tid + 256 * i; r[i] = p >> 5; c[i] = p & 31; }
    const float* inN = in + (size_t)n * CIN * 1024;
    for (int ic0 = 0; ic0 < CIN; ic0 += 4) {
        for (int t = tid; t < 4 * 1156; t += 256) {
            int j = t / 1156; int rem = t - j * 1156;
            int iy = rem / 34 - 1; int ix = rem % 34 - 1;
            float v = 0.f;
            if ((unsigned)iy < 32u && (unsigned)ix < 32u)
                v = inN[(size_t)(ic0 + j) * 1024 + iy * 32 + ix];
            sIn[t] = v;
        }
        for (int t = tid; t < 288; t += 256) {
            int j = t / 72; int rem = t - j * 72; int k = rem >> 3; int o = rem & 7;
            sW[t] = W[((size_t)(oc0 + o) * CIN + ic0 + j) * 9 + k];
        }
        __syncthreads();
#pragma unroll
        for (int j = 0; j < 4; j++) {
            const float* sp = sIn + j * 1156;
            const float* wp = sW + j * 72;
#pragma unroll
            for (int k = 0; k < 9; k++) {
                int ky = k / 3, kx = k % 3;
                float4 w0 = *(const float4*)(wp + k * 8);
                float4 w1 = *(const float4*)(wp + k * 8 + 4);
#pragma unroll
                for (int i = 0; i < 4; i++) {
                    float xv = sp[(r[i] + ky) * 34 + c[i] + kx];
                    acc[i][0] += w0.x * xv; acc[i][1] += w0.y * xv;
                    acc[i][2] += w0.z * xv; acc[i][3] += w0.w * xv;
                    acc[i][4] += w1.x * xv; acc[i][5] += w1.y * xv;
                    acc[i][6] += w1.z * xv; acc[i][7] += w1.w * xv;
                }
            }
        }
        __syncthreads();
    }
#pragma unroll
    for (int o = 0; o < 8; o++) {
        float b = HASB ? bias[oc0 + o] : 0.f;
#pragma unroll
        for (int i = 0; i < 4; i++) {
            float v = acc[i][o] + b;
            out[((size_t)n * 256 + oc0 + o) * 1024 + tid + 256 * i] = actf<ACT>(v);
        }
    }
}

// --------------------------- conv1x1 on 32x32 ------------------------------
template<int CIN, int COUT, int INACT, int OUTACT, bool HASB, bool RES>
__global__ __launch_bounds__(256) void conv1x1_k(const float* __restrict__ in,
        const float* __restrict__ W, const float* __restrict__ bias,
        const float* res, float* out) {
    int n = blockIdx.z, oc0 = blockIdx.y * 16;
    int p0 = blockIdx.x * 512 + threadIdx.x;   // and p0+256
    __shared__ float sW[CIN * 16];             // [ic][oc]
    for (int t = threadIdx.x; t < CIN * 16; t += 256) {
        int o = t / CIN, ic = t - o * CIN;
        sW[ic * 16 + o] = W[(size_t)(oc0 + o) * CIN + ic];
    }
    __syncthreads();
    float a0[16], a1[16];
#pragma unroll
    for (int o = 0; o < 16; o++) { a0[o] = 0.f; a1[o] = 0.f; }
    const float* inN = in + (size_t)n * CIN * 1024;
    for (int ic = 0; ic < CIN; ic++) {
        float x0 = actf<INACT>(inN[(size_t)ic * 1024 + p0]);
        float x1 = actf<INACT>(inN[(size_t)ic * 1024 + p0 + 256]);
        const float4* wp = (const float4*)(sW + ic * 16);
#pragma unroll
        for (int q = 0; q < 4; q++) {
            float4 w = wp[q];
            a0[4 * q + 0] += w.x * x0; a0[4 * q + 1] += w.y * x0;
            a0[4 * q + 2] += w.z * x0; a0[4 * q + 3] += w.w * x0;
            a1[4 * q + 0] += w.x * x1; a1[4 * q + 1] += w.y * x1;
            a1[4 * q + 2] += w.z * x1; a1[4 * q + 3] += w.w * x1;
        }
    }
#pragma unroll
    for (int o = 0; o < 16; o++) {
        float b = HASB ? bias[oc0 + o] : 0.f;
        size_t off = ((size_t)n * COUT + oc0 + o) * 1024;
        float v0 = a0[o] + b, v1 = a1[o] + b;
        if (RES) { v0 += res[off + p0]; v1 += res[off + p0 + 256]; }
        out[off + p0] = actf<OUTACT>(v0);
        out[off + p0 + 256] = actf<OUTACT>(v1);
    }
}

// ---------------- transpose z NCHW -> NHWC rows [16384,64] -----------------
__global__ __launch_bounds__(256) void transp_k(const float* __restrict__ zt,
        float* __restrict__ zr) {
    __shared__ float s[64][65];
    int n = blockIdx.y; int hw0 = blockIdx.x * 64;
    for (int t = threadIdx.x; t < 4096; t += 256) {
        int d = t >> 6, hw = t & 63;
        s[d][hw] = zt[((size_t)n * 64 + d) * 1024 + hw0 + hw];
    }
    __syncthreads();
    for (int t = threadIdx.x; t < 4096; t += 256) {
        int hw = t >> 6, d = t & 63;
        zr[((size_t)(n * 1024 + hw0 + hw)) * 64 + d] = s[d][hw];
    }
}

// ------------------------------- VQ argmin ---------------------------------
// scores = ||c||^2 - 2 z.c ; block: 128 positions x all 512 codes (8 chunks)
__global__ __launch_bounds__(256) void vq_argmin_k(const float* __restrict__ zr,
        const float* __restrict__ cb, int* __restrict__ ind) {
    __shared__ float lat[64 * 132];  // [d][pos], padded stride
    __shared__ float cbs[64 * 68];   // [d][k], padded stride (16B-aligned rows)
    __shared__ float cns[64];
    int tid = threadIdx.x;
    int pos0 = blockIdx.x * 128;
    for (int t = tid; t < 128 * 64; t += 256) {
        int p = t >> 6, d = t & 63;
        lat[d * 132 + p] = zr[(size_t)(pos0 + p) * 64 + d];
    }
    int px = tid >> 3, cx = tid & 7;
    float best[4]; int bidx[4];
#pragma unroll
    for (int i = 0; i < 4; i++) { best[i] = INFINITY; bidx[i] = 0; }
    for (int k0 = 0; k0 < 512; k0 += 64) {
        __syncthreads();
        for (int t = tid; t < 64 * 64; t += 256) {
            int k = t >> 6, d = t & 63;
            cbs[d * 68 + k] = cb[(size_t)(k0 + k) * 64 + d];
        }
        __syncthreads();
        if (tid < 64) {
            float s = 0.f;
            for (int d = 0; d < 64; d++) { float v = cbs[d * 68 + tid]; s += v * v; }
            cns[tid] = s;
        }
        __syncthreads();
        float acc[4][8];
#pragma unroll
        for (int i = 0; i < 4; i++)
#pragma unroll
            for (int j = 0; j < 8; j++) acc[i][j] = 0.f;
        for (int d = 0; d < 64; d++) {
            float4 c0 = *(const float4*)(cbs + d * 68 + cx * 8);
            float4 c1 = *(const float4*)(cbs + d * 68 + cx * 8 + 4);
#pragma unroll
            for (int i = 0; i < 4; i++) {
                float lv = lat[d * 132 + px * 4 + i];
                acc[i][0] += c0.x * lv; acc[i][1] += c0.y * lv;
                acc[i][2] += c0.z * lv; acc[i][3] += c0.w * lv;
                acc[i][4] += c1.x * lv; acc[i][5] += c1.y * lv;
                acc[i][6] += c1.z * lv; acc[i][7] += c1.w * lv;
            }
        }
#pragma unroll
        for (int i = 0; i < 4; i++)
#pragma unroll
            for (int j = 0; j < 8; j++) {
                float sc = cns[cx * 8 + j] - 2.f * acc[i][j];
                int idx = k0 + cx * 8 + j;
                if (sc < best[i]) { best[i] = sc; bidx[i] = idx; }
            }
    }
#pragma unroll
    for (int m = 1; m < 8; m <<= 1) {
#pragma unroll
        for (int i = 0; i < 4; i++) {
            float os = __shfl_xor(best[i], m);
            int   oi = __shfl_xor(bidx[i], m);
            if (os < best[i] || (os == best[i] && oi < bidx[i])) {
                best[i] = os; bidx[i] = oi;
            }
        }
    }
    if (cx == 0) {
#pragma unroll
        for (int i = 0; i < 4; i++) ind[pos0 + px * 4 + i] = bidx[i];
    }
}

// ---------------- VQ gather q (NCHW) + per-block loss partials -------------
__global__ __launch_bounds__(256) void vq_gather_k(const float* __restrict__ zr,
        const float* __restrict__ cb, const int* __restrict__ ind,
        float* __restrict__ q, float* __restrict__ part) {
    int pos = blockIdx.x * 256 + threadIdx.x;
    int n = pos >> 10, hw = pos & 1023;
    int idx = ind[pos];
    const float4* cp = (const float4*)(cb + (size_t)idx * 64);
    const float4* zp = (const float4*)(zr + (size_t)pos * 64);
    float sum = 0.f;
#pragma unroll
    for (int d4 = 0; d4 < 16; d4++) {
        float4 c = cp[d4], z = zp[d4];
        float dx = c.x - z.x, dy = c.y - z.y, dz = c.z - z.z, dw = c.w - z.w;
        sum += dx * dx + dy * dy + dz * dz + dw * dw;
        int d = d4 * 4;
        q[((size_t)n * 64 + d + 0) * 1024 + hw] = c.x;
        q[((size_t)n * 64 + d + 1) * 1024 + hw] = c.y;
        q[((size_t)n * 64 + d + 2) * 1024 + hw] = c.z;
        q[((size_t)n * 64 + d + 3) * 1024 + hw] = c.w;
    }
#pragma unroll
    for (int m = 1; m < 64; m <<= 1) sum += __shfl_xor(sum, m);
    __shared__ float sred[4];
    int lane = threadIdx.x & 63, wv = threadIdx.x >> 6;
    if (lane == 0) sred[wv] = sum;
    __syncthreads();
    if (threadIdx.x == 0)
        part[blockIdx.x] = sred[0] + sred[1] + sred[2] + sred[3];
}

__global__ void finalize_k(const float* __restrict__ part, float* __restrict__ out) {
    if (threadIdx.x == 0) {
        float s = 0.f;
        for (int k = 0; k < 64; k++) s += part[k];
        float m = s / 1048576.f;   // mean over 16384*64 elements
        out[786432] = m;           // embedding loss
        out[786433] = m;           // commitment loss (same forward value)
    }
}

// ------------------ conv transpose 4x4 s2 p1 (direct form) -----------------
// out[oy,ox] = sum_ic sum_{ky,kx valid} w[ic][oc][ky][kx] * x[ic][(oy+1-ky)/2][(ox+1-kx)/2]
template<int CIN, int COUT, int OCB, int WIN, int ROWS, int INACT, int OUTACT>
__global__ __launch_bounds__(256) void ct4x4_k(const float* __restrict__ in,
        const float* __restrict__ W, const float* __restrict__ bias,
        float* __restrict__ out) {
    const int WOUT = WIN * 2;
    const int NR = ROWS / 2 + 2, SC = WIN + 2;
    int n = blockIdx.z, oc0 = blockIdx.y * OCB, y0 = blockIdx.x * ROWS;
    int iy0 = y0 / 2 - 1;
    __shared__ float sIn[NR * SC];
    __shared__ float sW[16 * OCB];
    float acc[4][OCB];
#pragma unroll
    for (int i = 0; i < 4; i++)
#pragma unroll
        for (int o = 0; o < OCB; o++) acc[i][o] = 0.f;
    const float* inN = in + (size_t)n * CIN * WIN * WIN;
    int tid = threadIdx.x;
    for (int ic = 0; ic < CIN; ic++) {
        for (int t = tid; t < NR * SC; t += 256) {
            int ry = t / SC, rx = t - ry * SC;
            int iy = iy0 + ry, ix = rx - 1;
            float v = 0.f;
            if ((unsigned)iy < (unsigned)WIN && (unsigned)ix < (unsigned)WIN)
                v = actf<INACT>(inN[(size_t)ic * WIN * WIN + iy * WIN + ix]);
            sIn[t] = v;
        }
        for (int t = tid; t < 16 * OCB; t += 256) {
            int k = t / OCB, o = t - k * OCB;
            sW[t] = W[((size_t)ic * COUT + oc0 + o) * 16 + k];
        }
        __syncthreads();
#pragma unroll
        for (int i = 0; i < 4; i++) {
            int pix = tid + 256 * i;
            int oy = y0 + pix / WOUT, ox = pix & (WOUT - 1);
            int py = (oy + 1) & 1, pxp = (ox + 1) & 1;
#pragma unroll
            for (int kyi = 0; kyi < 2; kyi++) {
                int ky = py + 2 * kyi;
                int iy = (oy + 1 - ky) >> 1;
                int ry = iy - iy0;
#pragma unroll
                for (int kxi = 0; kxi < 2; kxi++) {
                    int kx = pxp + 2 * kxi;
                    int ix = (ox + 1 - kx) >> 1;
                    float xv = sIn[ry * SC + ix + 1];
                    const float* wp = sW + (ky * 4 + kx) * OCB;
#pragma unroll
                    for (int o = 0; o < OCB; o++) acc[i][o] += wp[o] * xv;
                }
            }
        }
        __syncthreads();
    }
#pragma unroll
    for (int o = 0; o < OCB; o++) {
        float b = bias[oc0 + o];
#pragma unroll
        for (int i = 0; i < 4; i++) {
            int pix = tid + 256 * i;
            int oy = y0 + pix / WOUT, ox = pix & (WOUT - 1);
            out[((size_t)n * COUT + oc0 + o) * (size_t)(WOUT * WOUT)
                + (size_t)oy * WOUT + ox] = actf<OUTACT>(acc[i][o] + b);
        }
    }
}

// ---------------------------------------------------------------------------
extern "C" void kernel_launch(void* const* d_in, const int* in_sizes, int n_in,
                              void* d_out, int out_size, void* d_ws, size_t ws_size,
                              hipStream_t stream) {
    const float* x    = (const float*)d_in[0];
    const float* ew0  = (const float*)d_in[1];
    const float* eb0  = (const float*)d_in[2];
    const float* ew1  = (const float*)d_in[3];
    const float* eb1  = (const float*)d_in[4];
    const float* ew2  = (const float*)d_in[5];
    const float* eb2  = (const float*)d_in[6];
    const float* erw3 = (const float*)d_in[7];
    const float* erw1 = (const float*)d_in[8];
    const float* ew3  = (const float*)d_in[9];
    const float* eb3  = (const float*)d_in[10];
    const float* cbk  = (const float*)d_in[11];
    const float* dw0  = (const float*)d_in[12];
    const float* db0  = (const float*)d_in[13];
    const float* drw3 = (const float*)d_in[14];
    const float* drw1 = (const float*)d_in[15];
    const float* tw0  = (const float*)d_in[16];
    const float* tb0  = (const float*)d_in[17];
    const float* tw1  = (const float*)d_in[18];
    const float* tb1  = (const float*)d_in[19];
    float* out = (float*)d_out;

    float* ws = (float*)d_ws;
    float* A  = ws;                    // [16,128,64,64] = 8388608
    float* Bb = A + 8388608;           // [16,256,32,32] = 4194304
    float* Cc = Bb + 4194304;          // [16,256,32,32]
    float* Dd = Cc + 4194304;          // [16,256,32,32]
    // B region is free after conv2 consumes it; reuse for VQ buffers
    float* Zt = Bb;                    // [16,64,32,32]   = 1048576
    float* Zr = Bb + 1048576;          // [16384,64]
    float* Qq = Bb + 2097152;          // [16,64,32,32]
    int*   IND = (int*)(Bb + 3145728); // [16384]
    float* PART = Bb + 3145728 + 16384; // [64]

    // ---------------- encoder ----------------
    conv0_k<<<dim3(16, 128, 16), 256, 0, stream>>>(x, ew0, eb0, A);
    conv1_k<<<dim3(32, 16), 256, 0, stream>>>(A, ew1, eb1, Bb);
    conv3x3_k<256, 2, true><<<dim3(32, 16), 256, 0, stream>>>(Bb, ew2, eb2, Cc);
    for (int i = 0; i < 6; i++) {
        conv3x3_k<256, 1, false><<<dim3(32, 16), 256, 0, stream>>>(
            Cc, erw3 + (size_t)i * 589824, nullptr, Dd);
        conv1x1_k<256, 256, 0, 0, false, true><<<dim3(2, 16, 16), 256, 0, stream>>>(
            Dd, erw1 + (size_t)i * 65536, nullptr, Cc, Cc);
    }
    conv1x1_k<256, 64, 2, 2, true, false><<<dim3(2, 4, 16), 256, 0, stream>>>(
        Cc, ew3, eb3, nullptr, Zt);

    // ---------------- vector quantization ----------------
    transp_k<<<dim3(16, 16), 256, 0, stream>>>(Zt, Zr);
    vq_argmin_k<<<128, 256, 0, stream>>>(Zr, cbk, IND);
    vq_gather_k<<<64, 256, 0, stream>>>(Zr, cbk, IND, Qq, PART);

    // ---------------- decoder ----------------
    conv3x3_k<64, 2, true><<<dim3(32, 16), 256, 0, stream>>>(Qq, dw0, db0, Cc);
    for (int i = 0; i < 6; i++) {
        conv3x3_k<256, 1, false><<<dim3(32, 16), 256, 0, stream>>>(
            Cc, drw3 + (size_t)i * 589824, nullptr, Dd);
        conv1x1_k<256, 256, 0, 0, false, true><<<dim3(2, 16, 16), 256, 0, stream>>>(
            Dd, drw1 + (size_t)i * 65536, nullptr, Cc, Cc);
    }
    // tw0: [16,256,32,32] -> [16,128,64,64], input lrelu (post-stack), out lrelu
    ct4x4_k<256, 128, 8, 32, 16, 2, 2><<<dim3(4, 16, 16), 256, 0, stream>>>(
        Cc, tw0, tb0, A);
    // tw1: [16,128,64,64] -> [16,3,128,128], tanh, straight into d_out
    ct4x4_k<128, 3, 3, 64, 8, 0, 3><<<dim3(16, 1, 16), 256, 0, stream>>>(
        A, tw1, tb1, out);

    finalize_k<<<1, 64, 0, stream>>>(PART, out);
}

// Round 2
// 1048.397 us; speedup vs baseline: 9.5281x; 9.5281x over previous
//
#include <hip/hip_runtime.h>
#include <math.h>

// ---------------------------------------------------------------------------
// VQ-VAE forward, bf16 MFMA implicit-GEMM version.
// Activations: padded NHWC bf16 (halo 2, zeroed each call).
// Weights: pre-permuted to [tap][oc][ic] bf16 each call.
// ---------------------------------------------------------------------------

typedef __attribute__((ext_vector_type(8))) short bf16x8;
typedef __attribute__((ext_vector_type(4))) float f32x4;

__device__ __forceinline__ float bf2f(short s) {
    unsigned u = ((unsigned)(unsigned short)s) << 16;
    return __builtin_bit_cast(float, u);
}
__device__ __forceinline__ unsigned short f2bfu(float f) {
    unsigned u = __builtin_bit_cast(unsigned, f);
    u = (u + 0x7fff + ((u >> 16) & 1)) >> 16;
    return (unsigned short)u;
}
__device__ __forceinline__ short f2bf(float f) { return (short)f2bfu(f); }

template<int ACT>
__device__ __forceinline__ float actf(float v) {
    if (ACT == 1) return fmaxf(v, 0.f);
    if (ACT == 2) return v > 0.f ? v : 0.01f * v;
    return v;
}

__device__ __forceinline__ void gload_lds16(const void* g, void* l) {
    __builtin_amdgcn_global_load_lds(
        (const __attribute__((address_space(1))) unsigned int*)g,
        (__attribute__((address_space(3))) unsigned int*)l, 16, 0, 0);
}

// ----------------------- weight prep: OIHW -> [t][oc][ic] bf16 -------------
__global__ __launch_bounds__(256) void prep_perm_k(const float* __restrict__ src,
        short* __restrict__ dst, int COUT, int CIN, int T, int total) {
    int i = blockIdx.x * 256 + threadIdx.x;
    if (i >= total) return;
    int ic = i % CIN; int r = i / CIN;
    int oc = r % COUT; r /= COUT;
    int t = r % T; int c = r / T;
    dst[i] = f2bf(src[(((size_t)c * COUT + oc) * CIN + ic) * T + t]);
}

// tw0 (Cin256,Cout128,4,4) -> [parity(4)][tap(4)][oc128][ic256]
__global__ __launch_bounds__(256) void prep_tw0_k(const float* __restrict__ src,
        short* __restrict__ dst) {
    int i = blockIdx.x * 256 + threadIdx.x;
    if (i >= 4 * 4 * 128 * 256) return;
    int ic = i & 255; int r = i >> 8;
    int oc = r & 127; r >>= 7;
    int tap = r & 3; int par = r >> 2;
    int py = par >> 1, px = par & 1, my = tap >> 1, mx = tap & 1;
    int ky = 2 * my + (py ^ 1), kx = 2 * mx + (px ^ 1);
    dst[i] = f2bf(src[(((size_t)ic * 128 + oc) * 4 + ky) * 4 + kx]);
}

// ------------------- unified MFMA implicit-GEMM conv -----------------------
// in: padded NHWC bf16, INW x INW pixel grid (square), halo 2.
// Wp: [tap][COUT][CIN] bf16.  Logical output grid 32x32 per image, M=16384.
// OUTMODE 0: padded-36 NHWC bf16 (+optional residual);  1: flat f32 [pix][COUT];
//         2: parity scatter into padded-68 NHWC bf16 (C=128).
template<int CIN, int COUT, int NTAPS, int TAPPAT, int SM, int INW,
         int OUTACT, bool RES, bool HASB, int OUTMODE, int BN>
__global__ __launch_bounds__(256) void gconv_k(
        const short* __restrict__ in, const short* __restrict__ Wp,
        const float* __restrict__ bias, const short* __restrict__ res,
        void* __restrict__ outp, int py, int px) {
    constexpr int KCH = CIN / 32;
    constexpr int NF = BN / 32;      // n-frags per wave
    constexpr int WN = BN / 2;       // wave n extent
    __shared__ short sA[128 * 32];
    __shared__ short sB[BN * 32];
    const int tid = threadIdx.x;
    const int lane = tid & 63, wv = tid >> 6;
    const int wr = wv >> 1, wc = wv & 1;
    const int pix0 = blockIdx.x * 128;
    const int oc0 = blockIdx.y * BN;

    const int sp = tid >> 2;
    const int swz = ((tid & 3) ^ (sp & 3)) * 8;
    int rbA[2];
#pragma unroll
    for (int rd = 0; rd < 2; rd++) {
        int pix = pix0 + sp + rd * 64;
        int b = pix >> 10, Y = (pix >> 5) & 31, X = pix & 31;
        rbA[rd] = ((b * INW + SM * Y + 2) * INW + (SM * X + 2)) * CIN + swz;
    }
    int wb0 = (oc0 + sp) * CIN + swz;
    int wb1 = (oc0 + sp + 64) * CIN + swz;

    f32x4 acc[4][NF];
#pragma unroll
    for (int i = 0; i < 4; i++)
#pragma unroll
        for (int j = 0; j < NF; j++) acc[i][j] = f32x4{0.f, 0.f, 0.f, 0.f};

    const int sslot = ((lane >> 4) ^ (lane & 3)) * 8;
    const int abase = (wr * 64 + (lane & 15)) * 32 + sslot;
    const int bbase = (wc * WN + (lane & 15)) * 32 + sslot;

    for (int t = 0; t < NTAPS; t++) {
        int rof, cof;
        if (TAPPAT == 0) { rof = 0; cof = 0; }
        else if (TAPPAT == 1) { rof = t / 3 - 1; cof = t % 3 - 1; }
        else if (TAPPAT == 2) { rof = t / 4 - 1; cof = t % 4 - 1; }
        else { int my = t >> 1, mx = t & 1;
               rof = (py == 0) ? -my : 1 - my;
               cof = (px == 0) ? -mx : 1 - mx; }
        const int tapoff = (rof * INW + cof) * CIN;
        const short* wt = Wp + (size_t)t * COUT * CIN;
        for (int c = 0; c < KCH; c++) {
            const int ic0 = c * 32;
            gload_lds16(in + rbA[0] + tapoff + ic0, (char*)sA + tid * 16);
            gload_lds16(in + rbA[1] + tapoff + ic0, (char*)sA + 4096 + tid * 16);
            gload_lds16(wt + wb0 + ic0, (char*)sB + tid * 16);
            if (BN == 128)
                gload_lds16(wt + wb1 + ic0, (char*)sB + 4096 + tid * 16);
            __syncthreads();
            bf16x8 af[4], bfm[NF];
#pragma unroll
            for (int mi = 0; mi < 4; mi++)
                af[mi] = *(const bf16x8*)(sA + abase + mi * 512);
#pragma unroll
            for (int ni = 0; ni < NF; ni++)
                bfm[ni] = *(const bf16x8*)(sB + bbase + ni * 512);
#pragma unroll
            for (int mi = 0; mi < 4; mi++)
#pragma unroll
                for (int ni = 0; ni < NF; ni++)
                    acc[mi][ni] = __builtin_amdgcn_mfma_f32_16x16x32_bf16(
                        af[mi], bfm[ni], acc[mi][ni], 0, 0, 0);
            __syncthreads();
        }
    }
    // epilogue
#pragma unroll
    for (int mi = 0; mi < 4; mi++) {
#pragma unroll
        for (int r = 0; r < 4; r++) {
            int pix = pix0 + wr * 64 + mi * 16 + (lane >> 4) * 4 + r;
            int b = pix >> 10, Y = (pix >> 5) & 31, X = pix & 31;
            size_t rowoff = 0;
            if (OUTMODE == 0)
                rowoff = (((size_t)b * 36 + Y + 2) * 36 + X + 2) * COUT;
            else if (OUTMODE == 2)
                rowoff = (((size_t)b * 68 + 2 * Y + py + 2) * 68 + 2 * X + px + 2) * 128;
#pragma unroll
            for (int ni = 0; ni < NF; ni++) {
                int col = oc0 + wc * WN + ni * 16 + (lane & 15);
                float v = acc[mi][ni][r];
                if (HASB) v += bias[col];
                if (OUTMODE == 1) {
                    ((float*)outp)[(size_t)pix * COUT + col] = actf<OUTACT>(v);
                } else {
                    size_t off = rowoff + col;
                    if (RES) v += bf2f(res[off]);
                    ((short*)outp)[off] = f2bf(actf<OUTACT>(v));
                }
            }
        }
    }
}

// ------------------------- conv0: 4x4 s2 p1, Cin=3 -------------------------
// x fp32 NCHW [16,3,128,128] -> P0 padded-68 NHWC bf16 [16][68][68][128], lrelu
__global__ __launch_bounds__(256) void conv0_k(const float* __restrict__ x,
        const float* __restrict__ W, const float* __restrict__ bias,
        short* __restrict__ P0) {
    __shared__ float sIn[3 * 18 * 66];
    __shared__ float sW[48 * 32];    // [ic*16+k][oc]
    int b = blockIdx.z, ocg = blockIdx.y, tile = blockIdx.x;
    int y0 = (tile >> 1) * 8, x0 = (tile & 1) * 32;
    int tid = threadIdx.x;
    for (int t = tid; t < 1536; t += 256) {
        int k = t >> 5, oc = t & 31;   // k = ic*16 + tap
        sW[t] = W[(size_t)(ocg * 32 + oc) * 48 + k];
    }
    for (int t = tid; t < 3 * 18 * 66; t += 256) {
        int ic = t / 1188; int rem = t - ic * 1188;
        int ry = rem / 66, rx = rem - ry * 66;
        int iy = 2 * y0 - 1 + ry, ix = 2 * x0 - 1 + rx;
        float v = 0.f;
        if ((unsigned)iy < 128u && (unsigned)ix < 128u)
            v = x[((size_t)b * 3 + ic) * 16384 + iy * 128 + ix];
        sIn[t] = v;
    }
    __syncthreads();
    int r = tid >> 5, cx = tid & 31;
    float acc[32];
#pragma unroll
    for (int o = 0; o < 32; o++) acc[o] = 0.f;
#pragma unroll
    for (int ic = 0; ic < 3; ic++) {
#pragma unroll
        for (int k = 0; k < 16; k++) {
            int ky = k >> 2, kx = k & 3;
            float xv = sIn[ic * 1188 + (2 * r + ky) * 66 + 2 * cx + kx];
            const float4* wp = (const float4*)(sW + (ic * 16 + k) * 32);
#pragma unroll
            for (int q = 0; q < 8; q++) {
                float4 w = wp[q];
                acc[4 * q + 0] += w.x * xv; acc[4 * q + 1] += w.y * xv;
                acc[4 * q + 2] += w.z * xv; acc[4 * q + 3] += w.w * xv;
            }
        }
    }
    size_t base = (((size_t)b * 68 + y0 + r + 2) * 68 + x0 + cx + 2) * 128 + ocg * 32;
#pragma unroll
    for (int q = 0; q < 16; q++) {
        float v0 = actf<2>(acc[2 * q] + bias[ocg * 32 + 2 * q]);
        float v1 = actf<2>(acc[2 * q + 1] + bias[ocg * 32 + 2 * q + 1]);
        ((int*)(P0 + base))[q] = (int)f2bfu(v0) | ((int)f2bfu(v1) << 16);
    }
}

// ------------------------------- VQ argmin ---------------------------------
__global__ __launch_bounds__(256) void vq_argmin_k(const float* __restrict__ zr,
        const float* __restrict__ cb, int* __restrict__ ind) {
    __shared__ float lat[64 * 132];
    __shared__ float cbs[64 * 68];
    __shared__ float cns[64];
    int tid = threadIdx.x;
    int pos0 = blockIdx.x * 128;
    for (int t = tid; t < 128 * 64; t += 256) {
        int p = t >> 6, d = t & 63;
        lat[d * 132 + p] = zr[(size_t)(pos0 + p) * 64 + d];
    }
    int px = tid >> 3, cx = tid & 7;
    float best[4]; int bidx[4];
#pragma unroll
    for (int i = 0; i < 4; i++) { best[i] = INFINITY; bidx[i] = 0; }
    for (int k0 = 0; k0 < 512; k0 += 64) {
        __syncthreads();
        for (int t = tid; t < 64 * 64; t += 256) {
            int k = t >> 6, d = t & 63;
            cbs[d * 68 + k] = cb[(size_t)(k0 + k) * 64 + d];
        }
        __syncthreads();
        if (tid < 64) {
            float s = 0.f;
            for (int d = 0; d < 64; d++) { float v = cbs[d * 68 + tid]; s += v * v; }
            cns[tid] = s;
        }
        __syncthreads();
        float acc[4][8];
#pragma unroll
        for (int i = 0; i < 4; i++)
#pragma unroll
            for (int j = 0; j < 8; j++) acc[i][j] = 0.f;
        for (int d = 0; d < 64; d++) {
            float4 c0 = *(const float4*)(cbs + d * 68 + cx * 8);
            float4 c1 = *(const float4*)(cbs + d * 68 + cx * 8 + 4);
#pragma unroll
            for (int i = 0; i < 4; i++) {
                float lv = lat[d * 132 + px * 4 + i];
                acc[i][0] += c0.x * lv; acc[i][1] += c0.y * lv;
                acc[i][2] += c0.z * lv; acc[i][3] += c0.w * lv;
                acc[i][4] += c1.x * lv; acc[i][5] += c1.y * lv;
                acc[i][6] += c1.z * lv; acc[i][7] += c1.w * lv;
            }
        }
#pragma unroll
        for (int i = 0; i < 4; i++)
#pragma unroll
            for (int j = 0; j < 8; j++) {
                float sc = cns[cx * 8 + j] - 2.f * acc[i][j];
                int idx = k0 + cx * 8 + j;
                if (sc < best[i]) { best[i] = sc; bidx[i] = idx; }
            }
    }
#pragma unroll
    for (int m = 1; m < 8; m <<= 1) {
#pragma unroll
        for (int i = 0; i < 4; i++) {
            float os = __shfl_xor(best[i], m);
            int   oi = __shfl_xor(bidx[i], m);
            if (os < best[i] || (os == best[i] && oi < bidx[i])) {
                best[i] = os; bidx[i] = oi;
            }
        }
    }
    if (cx == 0) {
#pragma unroll
        for (int i = 0; i < 4; i++) ind[pos0 + px * 4 + i] = bidx[i];
    }
}

// -------------- VQ gather -> Pq padded bf16 + loss partials ----------------
__global__ __launch_bounds__(256) void vq_gather_k(const float* __restrict__ zr,
        const float* __restrict__ cb, const int* __restrict__ ind,
        short* __restrict__ q, float* __restrict__ part) {
    int pos = blockIdx.x * 256 + threadIdx.x;
    int b = pos >> 10, hw = pos & 1023, y = hw >> 5, xx = hw & 31;
    int idx = ind[pos];
    const float4* cp = (const float4*)(cb + (size_t)idx * 64);
    const float4* zp = (const float4*)(zr + (size_t)pos * 64);
    size_t qb = (((size_t)b * 36 + y + 2) * 36 + xx + 2) * 64;
    float sum = 0.f;
#pragma unroll
    for (int d4 = 0; d4 < 16; d4++) {
        float4 c = cp[d4], z = zp[d4];
        float dx = c.x - z.x, dy = c.y - z.y, dz = c.z - z.z, dw = c.w - z.w;
        sum += dx * dx + dy * dy + dz * dz + dw * dw;
        ((int*)(q + qb))[2 * d4] = (int)f2bfu(c.x) | ((int)f2bfu(c.y) << 16);
        ((int*)(q + qb))[2 * d4 + 1] = (int)f2bfu(c.z) | ((int)f2bfu(c.w) << 16);
    }
#pragma unroll
    for (int m = 1; m < 64; m <<= 1) sum += __shfl_xor(sum, m);
    __shared__ float sred[4];
    int lane = threadIdx.x & 63, wvv = threadIdx.x >> 6;
    if (lane == 0) sred[wvv] = sum;
    __syncthreads();
    if (threadIdx.x == 0)
        part[blockIdx.x] = sred[0] + sred[1] + sred[2] + sred[3];
}

__global__ void finalize_k(const float* __restrict__ part, float* __restrict__ out) {
    if (threadIdx.x == 0) {
        float s = 0.f;
        for (int k = 0; k < 64; k++) s += part[k];
        float m = s / 1048576.f;
        out[786432] = m;
        out[786433] = m;
    }
}

// -------- tw1: ConvT 4x4 s2 p1, 128->3, input P4 padded-68 bf16, tanh ------
__global__ __launch_bounds__(256) void tw1_k(const short* __restrict__ in,
        const float* __restrict__ W, const float* __restrict__ bias,
        float* __restrict__ out) {
    __shared__ float sW[16 * 128 * 4];   // [k][ic][4] (oc0..2, pad)
    int b = blockIdx.y, y0 = blockIdx.x * 8;
    int tid = threadIdx.x;
    for (int t = tid; t < 2048; t += 256) {
        int k = t >> 7, ic = t & 127;
        float4 v;
        v.x = W[((size_t)ic * 3 + 0) * 16 + k];
        v.y = W[((size_t)ic * 3 + 1) * 16 + k];
        v.z = W[((size_t)ic * 3 + 2) * 16 + k];
        v.w = 0.f;
        *(float4*)&sW[t * 4] = v;
    }
    __syncthreads();
    int r = tid >> 5, g = tid & 31;
    int oy = y0 + r, py = oy & 1, Y = oy >> 1, pxp = g & 1;
    float acc[4][3];
#pragma unroll
    for (int p = 0; p < 4; p++)
#pragma unroll
        for (int o = 0; o < 3; o++) acc[p][o] = 0.f;
#pragma unroll
    for (int my = 0; my < 2; my++) {
        int iy = Y + ((py == 0) ? -my : 1 - my) + 2;
        const short* rowp = in + (((size_t)b * 68 + iy) * 68) * 128;
        int ky = 2 * my + (py ^ 1);
#pragma unroll
        for (int mx = 0; mx < 2; mx++) {
            int kx = 2 * mx + (pxp ^ 1);
            int cof = ((pxp == 0) ? -mx : 1 - mx) + 2;
            const float* wbase = &sW[((ky * 4 + kx) * 128) * 4];
            const short* pptr[4];
#pragma unroll
            for (int p = 0; p < 4; p++) {
                int X = ((g + 32 * p) >> 1) + cof;
                pptr[p] = rowp + (size_t)X * 128;
            }
            for (int icb = 0; icb < 16; icb++) {
                bf16x8 v[4];
#pragma unroll
                for (int p = 0; p < 4; p++)
                    v[p] = *(const bf16x8*)(pptr[p] + icb * 8);
#pragma unroll
                for (int j = 0; j < 8; j++) {
                    float4 w = *(const float4*)&wbase[(icb * 8 + j) * 4];
#pragma unroll
                    for (int p = 0; p < 4; p++) {
                        float xv = bf2f(v[p][j]);
                        acc[p][0] += w.x * xv;
                        acc[p][1] += w.y * xv;
                        acc[p][2] += w.z * xv;
                    }
                }
            }
        }
    }
#pragma unroll
    for (int p = 0; p < 4; p++) {
        int ox = g + 32 * p;
#pragma unroll
        for (int o = 0; o < 3; o++)
            out[(((size_t)b * 3 + o) << 14) + oy * 128 + ox] =
                tanhf(acc[p][o] + bias[o]);
    }
}

// ---------------------------------------------------------------------------
extern "C" void kernel_launch(void* const* d_in, const int* in_sizes, int n_in,
                              void* d_out, int out_size, void* d_ws, size_t ws_size,
                              hipStream_t stream) {
    const float* x    = (const float*)d_in[0];
    const float* ew0  = (const float*)d_in[1];
    const float* eb0  = (const float*)d_in[2];
    const float* ew1  = (const float*)d_in[3];
    const float* eb1  = (const float*)d_in[4];
    const float* ew2  = (const float*)d_in[5];
    const float* eb2  = (const float*)d_in[6];
    const float* erw3 = (const float*)d_in[7];
    const float* erw1 = (const float*)d_in[8];
    const float* ew3  = (const float*)d_in[9];
    const float* eb3  = (const float*)d_in[10];
    const float* cbk  = (const float*)d_in[11];
    const float* dw0  = (const float*)d_in[12];
    const float* db0  = (const float*)d_in[13];
    const float* drw3 = (const float*)d_in[14];
    const float* drw1 = (const float*)d_in[15];
    const float* tw0  = (const float*)d_in[16];
    const float* tb0  = (const float*)d_in[17];
    const float* tw1  = (const float*)d_in[18];
    const float* tb1  = (const float*)d_in[19];
    float* out = (float*)d_out;

    short* S = (short*)d_ws;
    short* P0  = S;                       // [16][68][68][128]  9,469,952
    short* PB  = P0 + 9469952;            // [16][36][36][256]  5,308,416
    short* PC  = PB + 5308416;            // [16][36][36][256]
    short* Pq  = PC + 5308416;            // [16][36][36][64]   1,327,104
    short* Wp1 = Pq + 1327104;            // 16*256*128
    short* We2 = Wp1 + 524288;            // 9*256*256
    short* Wer3 = We2 + 589824;           // 6*9*256*256
    short* We11 = Wer3 + 3538944;         // 6*256*256
    short* Wz   = We11 + 393216;          // 64*256
    short* Wd0  = Wz + 16384;             // 9*256*64
    short* Wdr3 = Wd0 + 147456;           // 6*9*256*256
    short* Wdr1 = Wdr3 + 3538944;         // 6*256*256
    short* Wt0  = Wdr1 + 393216;          // 16*128*256
    float* F   = (float*)(S + 31080448);
    float* Zr  = F;                       // [16384][64]
    float* PART = Zr + 1048576;           // [64]
    int*   IND = (int*)(PART + 64);       // [16384]

    // zero activation region (halos must be 0)
    hipMemsetAsync(d_ws, 0, (size_t)21413888 * 2, stream);

    // ---------------- weight prep ----------------
    auto gp = [](int n) { return dim3((n + 255) / 256); };
    prep_perm_k<<<gp(524288), 256, 0, stream>>>(ew1, Wp1, 256, 128, 16, 524288);
    prep_perm_k<<<gp(589824), 256, 0, stream>>>(ew2, We2, 256, 256, 9, 589824);
    prep_perm_k<<<gp(3538944), 256, 0, stream>>>(erw3, Wer3, 256, 256, 9, 3538944);
    prep_perm_k<<<gp(393216), 256, 0, stream>>>(erw1, We11, 256, 256, 1, 393216);
    prep_perm_k<<<gp(16384), 256, 0, stream>>>(ew3, Wz, 64, 256, 1, 16384);
    prep_perm_k<<<gp(147456), 256, 0, stream>>>(dw0, Wd0, 256, 64, 9, 147456);
    prep_perm_k<<<gp(3538944), 256, 0, stream>>>(drw3, Wdr3, 256, 256, 9, 3538944);
    prep_perm_k<<<gp(393216), 256, 0, stream>>>(drw1, Wdr1, 256, 256, 1, 393216);
    prep_tw0_k<<<gp(524288), 256, 0, stream>>>(tw0, Wt0);

    // ---------------- encoder ----------------
    conv0_k<<<dim3(16, 4, 16), 256, 0, stream>>>(x, ew0, eb0, P0);
    // conv1: 4x4 s2, 128->256, lrelu
    gconv_k<128, 256, 16, 2, 2, 68, 2, false, true, 0, 128>
        <<<dim3(128, 2), 256, 0, stream>>>(P0, Wp1, eb1, nullptr, PB, 0, 0);
    // ew2: 3x3, 256->256, lrelu
    gconv_k<256, 256, 9, 1, 1, 36, 2, false, true, 0, 128>
        <<<dim3(128, 2), 256, 0, stream>>>(PB, We2, eb2, nullptr, PC, 0, 0);
    // encoder residual stack
    for (int i = 0; i < 6; i++) {
        gconv_k<256, 256, 9, 1, 1, 36, 1, false, false, 0, 128>
            <<<dim3(128, 2), 256, 0, stream>>>(PC, Wer3 + (size_t)i * 589824,
                                               nullptr, nullptr, PB, 0, 0);
        if (i < 5)
            gconv_k<256, 256, 1, 0, 1, 36, 0, true, false, 0, 128>
                <<<dim3(128, 2), 256, 0, stream>>>(PB, We11 + (size_t)i * 65536,
                                                   nullptr, PC, PC, 0, 0);
        else  // last: fuse the post-stack lrelu
            gconv_k<256, 256, 1, 0, 1, 36, 2, true, false, 0, 128>
                <<<dim3(128, 2), 256, 0, stream>>>(PB, We11 + (size_t)i * 65536,
                                                   nullptr, PC, PC, 0, 0);
    }
    // z = lrelu(conv1x1 256->64), fp32 flat [pix][64]
    gconv_k<256, 64, 1, 0, 1, 36, 2, false, true, 1, 64>
        <<<dim3(128, 1), 256, 0, stream>>>(PC, Wz, eb3, nullptr, Zr, 0, 0);

    // ---------------- vector quantization ----------------
    vq_argmin_k<<<128, 256, 0, stream>>>(Zr, cbk, IND);
    vq_gather_k<<<64, 256, 0, stream>>>(Zr, cbk, IND, Pq, PART);

    // ---------------- decoder ----------------
    gconv_k<64, 256, 9, 1, 1, 36, 2, false, true, 0, 128>
        <<<dim3(128, 2), 256, 0, stream>>>(Pq, Wd0, db0, nullptr, PC, 0, 0);
    for (int i = 0; i < 6; i++) {
        gconv_k<256, 256, 9, 1, 1, 36, 1, false, false, 0, 128>
            <<<dim3(128, 2), 256, 0, stream>>>(PC, Wdr3 + (size_t)i * 589824,
                                               nullptr, nullptr, PB, 0, 0);
        if (i < 5)
            gconv_k<256, 256, 1, 0, 1, 36, 0, true, false, 0, 128>
                <<<dim3(128, 2), 256, 0, stream>>>(PB, Wdr1 + (size_t)i * 65536,
                                                   nullptr, PC, PC, 0, 0);
        else  // fuse post-stack lrelu
            gconv_k<256, 256, 1, 0, 1, 36, 2, true, false, 0, 128>
                <<<dim3(128, 2), 256, 0, stream>>>(PB, Wdr1 + (size_t)i * 65536,
                                                   nullptr, PC, PC, 0, 0);
    }
    // tw0 ConvT 256->128 as 4 parity GEMMs, lrelu, into P0 (reused as P4)
    for (int par = 0; par < 4; par++) {
        int py = par >> 1, px = par & 1;
        gconv_k<256, 128, 4, 3, 1, 36, 2, false, true, 2, 128>
            <<<dim3(128, 1), 256, 0, stream>>>(PC, Wt0 + (size_t)par * 131072,
                                               tb0, nullptr, P0, py, px);
    }
    // tw1 ConvT 128->3, tanh, into d_out
    tw1_k<<<dim3(16, 16), 256, 0, stream>>>(P0, tw1, tb1, out);

    finalize_k<<<1, 64, 0, stream>>>(PART, out);
}